// Round 9
// baseline (142.519 us; speedup 1.0000x reference)
//
#include <hip/hip_runtime.h>

#define B     512
#define NBG   10000
#define F     32
#define H     128
#define CHUNK 20
#define NBLK  500      // NBLK*CHUNK == NBG exactly
#define RB    8        // batch rows per MLP block
#define MLPBLK (B / RB)     // 64

// ---------------- Kernel A: MLP -> XT[f][b], babsT[f][b] ----------------
__global__ __launch_bounds__(128) void prep_kernel(
    const float* __restrict__ X,
    const float* __restrict__ W0, const float* __restrict__ b0,
    const float* __restrict__ W1, const float* __restrict__ b1,
    const float* __restrict__ Wout, const float* __restrict__ bout,
    float* __restrict__ XT,
    float* __restrict__ babsT)
{
    __shared__ __align__(16) float xr[RB * F];
    __shared__ __align__(16) float h0[RB * H];
    __shared__ __align__(16) float h1[RB * H];
    const int t  = threadIdx.x;
    const int r0 = blockIdx.x * RB;

    for (int i = t; i < RB * F; i += 128) {
        int r = i >> 5, f = i & 31;
        float xv = X[(r0 + r) * F + f];
        xr[r * F + f] = xv;
        XT[f * B + r0 + r] = xv;
    }
    __syncthreads();

    float acc[RB];
    #pragma unroll
    for (int r = 0; r < RB; ++r) acc[r] = b0[t];
    #pragma unroll
    for (int f4 = 0; f4 < F / 4; ++f4) {
        float wa = W0[(4*f4+0)*H + t];
        float wb = W0[(4*f4+1)*H + t];
        float wc = W0[(4*f4+2)*H + t];
        float wd = W0[(4*f4+3)*H + t];
        #pragma unroll
        for (int r = 0; r < RB; ++r) {
            float4 xv = *(const float4*)&xr[r * F + 4*f4];
            acc[r] += xv.x*wa + xv.y*wb + xv.z*wc + xv.w*wd;
        }
    }
    #pragma unroll
    for (int r = 0; r < RB; ++r) h0[r * H + t] = fmaxf(acc[r], 0.f);
    __syncthreads();

    #pragma unroll
    for (int r = 0; r < RB; ++r) acc[r] = b1[t];
    #pragma unroll 8
    for (int j4 = 0; j4 < H / 4; ++j4) {
        float wa = W1[(4*j4+0)*H + t];
        float wb = W1[(4*j4+1)*H + t];
        float wc = W1[(4*j4+2)*H + t];
        float wd = W1[(4*j4+3)*H + t];
        #pragma unroll
        for (int r = 0; r < RB; ++r) {
            float4 hv = *(const float4*)&h0[r * H + 4*j4];
            acc[r] += hv.x*wa + hv.y*wb + hv.z*wc + hv.w*wd;
        }
    }
    #pragma unroll
    for (int r = 0; r < RB; ++r) h1[r * H + t] = fmaxf(acc[r], 0.f);
    __syncthreads();

    for (int i = t; i < RB * F; i += 128) {
        int r = i >> 5, f = i & 31;
        float a = bout[f];
        #pragma unroll 8
        for (int j4 = 0; j4 < H / 4; ++j4) {
            float4 hv = *(const float4*)&h1[r * H + 4*j4];
            a += hv.x*Wout[(4*j4+0)*F + f] + hv.y*Wout[(4*j4+1)*F + f]
               + hv.z*Wout[(4*j4+2)*F + f] + hv.w*Wout[(4*j4+3)*F + f];
        }
        babsT[f * B + r0 + r] = fabsf(a);
    }
}

// ---------------- Kernel B: NW partial sums, split-F register passes ----------------
// Thread = batch row b. Block = chunk of CHUNK=20 points staged in LDS
// (lane-uniform ds_read_b128 broadcast). F processed in TWO passes of 16
// features so peak per-thread state is xq[16]+bv[16]+d[20] ~= 60 VGPR --
// small enough that the allocator keeps it resident instead of re-loading
// from L2 every iteration (the r5-r8 plateau: VGPR_Count=44 proved remat;
// 1.3 GB of L2 re-reads ~= 38 us).
__global__ __launch_bounds__(512, 4) void nw_partial(
    const float* __restrict__ XT,
    const float* __restrict__ babsT,
    const float* __restrict__ xbg,
    const float* __restrict__ ybg,
    float* __restrict__ psw,
    float* __restrict__ pswy)
{
    __shared__ __align__(16) float tile[CHUNK * F];   // 2560 B
    __shared__ float ytile[CHUNK];

    const int b  = threadIdx.x;
    const int n0 = blockIdx.x * CHUNK;

    // stage chunk: 640 contiguous floats + 20 y values (coalesced)
    tile[b] = xbg[n0 * F + b];
    if (b < CHUNK * F - 512) tile[512 + b] = xbg[n0 * F + 512 + b];
    if (b < CHUNK) ytile[b] = ybg[n0 + b];
    __syncthreads();

    const float4* t4 = (const float4*)tile;
    float d[CHUNK];
    #pragma unroll
    for (int j = 0; j < CHUNK; ++j) d[j] = 0.f;

    // ---- pass 0: features 0..15 ----
    {
        float xq[16], bv[16];
        #pragma unroll
        for (int f = 0; f < 16; ++f) {
            xq[f] = XT[f * B + b];          // coalesced 256B/wave
            bv[f] = babsT[f * B + b];
        }
        #pragma unroll
        for (int f = 0; f < 16; ++f)
            asm volatile("" : "+v"(xq[f]), "+v"(bv[f]));
        #pragma unroll
        for (int j = 0; j < CHUNK; ++j) {
            float da = 0.f, db = 0.f;
            #pragma unroll
            for (int q = 0; q < 4; ++q) {
                float4 v = t4[j * 8 + q];   // lane-uniform -> broadcast
                da += bv[4*q+0] * fabsf(xq[4*q+0] - v.x);
                db += bv[4*q+1] * fabsf(xq[4*q+1] - v.y);
                da += bv[4*q+2] * fabsf(xq[4*q+2] - v.z);
                db += bv[4*q+3] * fabsf(xq[4*q+3] - v.w);
            }
            d[j] += da + db;
        }
    }
    // ---- pass 1: features 16..31 ----
    {
        float xq[16], bv[16];
        #pragma unroll
        for (int f = 0; f < 16; ++f) {
            xq[f] = XT[(16 + f) * B + b];
            bv[f] = babsT[(16 + f) * B + b];
        }
        #pragma unroll
        for (int f = 0; f < 16; ++f)
            asm volatile("" : "+v"(xq[f]), "+v"(bv[f]));
        #pragma unroll
        for (int j = 0; j < CHUNK; ++j) {
            float da = 0.f, db = 0.f;
            #pragma unroll
            for (int q = 0; q < 4; ++q) {
                float4 v = t4[j * 8 + 4 + q];   // lane-uniform -> broadcast
                da += bv[4*q+0] * fabsf(xq[4*q+0] - v.x);
                db += bv[4*q+1] * fabsf(xq[4*q+1] - v.y);
                da += bv[4*q+2] * fabsf(xq[4*q+2] - v.z);
                db += bv[4*q+3] * fabsf(xq[4*q+3] - v.w);
            }
            d[j] += da + db;
        }
    }

    float sw = 0.f, swy = 0.f;
    #pragma unroll
    for (int j = 0; j < CHUNK; ++j) {
        float w = __expf(-d[j]);
        sw  += w;
        swy += w * ytile[j];
    }

    psw [blockIdx.x * B + b] = sw;    // coalesced
    pswy[blockIdx.x * B + b] = swy;
}

// ---------------- Kernel C: combine partials, normalize ----------------
__global__ __launch_bounds__(64) void nw_final(
    const float* __restrict__ psw,
    const float* __restrict__ pswy,
    float* __restrict__ out)
{
    const int b = blockIdx.x;
    const int t = threadIdx.x;

    float sw = 0.f, swy = 0.f;
    for (int c = t; c < NBLK; c += 64) {
        sw  += psw [c * B + b];
        swy += pswy[c * B + b];
    }
    #pragma unroll
    for (int off = 32; off > 0; off >>= 1) {
        sw  += __shfl_down(sw,  off);
        swy += __shfl_down(swy, off);
    }
    if (t == 0) out[b] = swy / sw;
}

extern "C" void kernel_launch(void* const* d_in, const int* in_sizes, int n_in,
                              void* d_out, int out_size, void* d_ws, size_t ws_size,
                              hipStream_t stream)
{
    const float* X    = (const float*)d_in[0];
    const float* xbg  = (const float*)d_in[1];
    const float* ybg  = (const float*)d_in[2];
    const float* W0   = (const float*)d_in[3];
    const float* b0   = (const float*)d_in[4];
    const float* W1   = (const float*)d_in[5];
    const float* b1   = (const float*)d_in[6];
    const float* Wout = (const float*)d_in[7];
    const float* bout = (const float*)d_in[8];
    float* out = (float*)d_out;

    float* XT    = (float*)d_ws;              // F*B
    float* babsT = XT + F * B;                // F*B
    float* psw   = babsT + F * B;             // NBLK*B (1 MB)
    float* pswy  = psw + NBLK * B;            // NBLK*B (1 MB)

    prep_kernel<<<MLPBLK, 128, 0, stream>>>(X, W0, b0, W1, b1, Wout, bout, XT, babsT);
    nw_partial<<<NBLK, B, 0, stream>>>(XT, babsT, xbg, ybg, psw, pswy);
    nw_final<<<B, 64, 0, stream>>>(psw, pswy, out);
}

// Round 10
// 47.174 us; speedup vs baseline: 3.0211x; 3.0211x over previous
//
#include <hip/hip_runtime.h>

#define B     512
#define NBG   10000
#define F     32
#define H     128
#define CHUNK 20
#define NBLK  500      // NBLK*CHUNK == NBG exactly
#define RB    8        // batch rows per MLP block
#define MLPBLK (B / RB)     // 64

// ---------------- Kernel A: MLP -> XT[f][b], babsT[f][b] ----------------
__global__ __launch_bounds__(128) void prep_kernel(
    const float* __restrict__ X,
    const float* __restrict__ W0, const float* __restrict__ b0,
    const float* __restrict__ W1, const float* __restrict__ b1,
    const float* __restrict__ Wout, const float* __restrict__ bout,
    float* __restrict__ XT,
    float* __restrict__ babsT)
{
    __shared__ __align__(16) float xr[RB * F];
    __shared__ __align__(16) float h0[RB * H];
    __shared__ __align__(16) float h1[RB * H];
    const int t  = threadIdx.x;
    const int r0 = blockIdx.x * RB;

    for (int i = t; i < RB * F; i += 128) {
        int r = i >> 5, f = i & 31;
        float xv = X[(r0 + r) * F + f];
        xr[r * F + f] = xv;
        XT[f * B + r0 + r] = xv;
    }
    __syncthreads();

    float acc[RB];
    #pragma unroll
    for (int r = 0; r < RB; ++r) acc[r] = b0[t];
    #pragma unroll
    for (int f4 = 0; f4 < F / 4; ++f4) {
        float wa = W0[(4*f4+0)*H + t];
        float wb = W0[(4*f4+1)*H + t];
        float wc = W0[(4*f4+2)*H + t];
        float wd = W0[(4*f4+3)*H + t];
        #pragma unroll
        for (int r = 0; r < RB; ++r) {
            float4 xv = *(const float4*)&xr[r * F + 4*f4];
            acc[r] += xv.x*wa + xv.y*wb + xv.z*wc + xv.w*wd;
        }
    }
    #pragma unroll
    for (int r = 0; r < RB; ++r) h0[r * H + t] = fmaxf(acc[r], 0.f);
    __syncthreads();

    #pragma unroll
    for (int r = 0; r < RB; ++r) acc[r] = b1[t];
    #pragma unroll 8
    for (int j4 = 0; j4 < H / 4; ++j4) {
        float wa = W1[(4*j4+0)*H + t];
        float wb = W1[(4*j4+1)*H + t];
        float wc = W1[(4*j4+2)*H + t];
        float wd = W1[(4*j4+3)*H + t];
        #pragma unroll
        for (int r = 0; r < RB; ++r) {
            float4 hv = *(const float4*)&h0[r * H + 4*j4];
            acc[r] += hv.x*wa + hv.y*wb + hv.z*wc + hv.w*wd;
        }
    }
    #pragma unroll
    for (int r = 0; r < RB; ++r) h1[r * H + t] = fmaxf(acc[r], 0.f);
    __syncthreads();

    for (int i = t; i < RB * F; i += 128) {
        int r = i >> 5, f = i & 31;
        float a = bout[f];
        #pragma unroll 8
        for (int j4 = 0; j4 < H / 4; ++j4) {
            float4 hv = *(const float4*)&h1[r * H + 4*j4];
            a += hv.x*Wout[(4*j4+0)*F + f] + hv.y*Wout[(4*j4+1)*F + f]
               + hv.z*Wout[(4*j4+2)*F + f] + hv.w*Wout[(4*j4+3)*F + f];
        }
        babsT[f * B + r0 + r] = fabsf(a);
    }
}

// ---------------- Kernel B: NW partial sums ----------------
// Thread = batch row b. Block = chunk of CHUNK=20 points staged in LDS
// (lane-uniform ds_read_b128 broadcast, conflict-free).
// amdgpu_waves_per_eu(2,4): MAX 4 waves/EU -> VGPR budget 128-256, so the
// allocator has NO incentive to remat (r5-r8: L2 re-reads, VGPR=44) or
// spill (r9: scratch->HBM, 140MB FETCH) the 84-float working set.
__global__ __launch_bounds__(512)
__attribute__((amdgpu_waves_per_eu(2, 4)))
void nw_partial(
    const float* __restrict__ XT,
    const float* __restrict__ babsT,
    const float* __restrict__ xbg,
    const float* __restrict__ ybg,
    float* __restrict__ psw,
    float* __restrict__ pswy)
{
    __shared__ __align__(16) float tile[CHUNK * F];   // 2560 B
    __shared__ float ytile[CHUNK];

    const int b  = threadIdx.x;
    const int n0 = blockIdx.x * CHUNK;

    // stage chunk: 640 contiguous floats + 20 y values (coalesced)
    tile[b] = xbg[n0 * F + b];
    if (b < CHUNK * F - 512) tile[512 + b] = xbg[n0 * F + 512 + b];
    if (b < CHUNK) ytile[b] = ybg[n0 + b];

    // preload row data (independent of LDS staging, overlaps it)
    float xq[F], bv[F];
    #pragma unroll
    for (int f = 0; f < F; ++f) {
        xq[f] = XT[f * B + b];          // coalesced 256B/wave, L2-resident
        bv[f] = babsT[f * B + b];
    }
    __syncthreads();

    const float4* t4 = (const float4*)tile;
    float d[CHUNK];
    #pragma unroll
    for (int j = 0; j < CHUNK; ++j) d[j] = 0.f;

    #pragma unroll 4
    for (int j = 0; j < CHUNK; ++j) {
        float da = 0.f, db = 0.f;
        #pragma unroll
        for (int q = 0; q < F / 4; ++q) {
            float4 v = t4[j * (F / 4) + q];   // lane-uniform addr -> broadcast
            da += bv[4*q+0] * fabsf(xq[4*q+0] - v.x);
            db += bv[4*q+1] * fabsf(xq[4*q+1] - v.y);
            da += bv[4*q+2] * fabsf(xq[4*q+2] - v.z);
            db += bv[4*q+3] * fabsf(xq[4*q+3] - v.w);
        }
        d[j] = da + db;
    }

    float sw = 0.f, swy = 0.f;
    #pragma unroll
    for (int j = 0; j < CHUNK; ++j) {
        float w = __expf(-d[j]);
        sw  += w;
        swy += w * ytile[j];
    }

    psw [blockIdx.x * B + b] = sw;    // coalesced
    pswy[blockIdx.x * B + b] = swy;
}

// ---------------- Kernel C: combine partials, normalize ----------------
__global__ __launch_bounds__(64) void nw_final(
    const float* __restrict__ psw,
    const float* __restrict__ pswy,
    float* __restrict__ out)
{
    const int b = blockIdx.x;
    const int t = threadIdx.x;

    float sw = 0.f, swy = 0.f;
    for (int c = t; c < NBLK; c += 64) {
        sw  += psw [c * B + b];
        swy += pswy[c * B + b];
    }
    #pragma unroll
    for (int off = 32; off > 0; off >>= 1) {
        sw  += __shfl_down(sw,  off);
        swy += __shfl_down(swy, off);
    }
    if (t == 0) out[b] = swy / sw;
}

extern "C" void kernel_launch(void* const* d_in, const int* in_sizes, int n_in,
                              void* d_out, int out_size, void* d_ws, size_t ws_size,
                              hipStream_t stream)
{
    const float* X    = (const float*)d_in[0];
    const float* xbg  = (const float*)d_in[1];
    const float* ybg  = (const float*)d_in[2];
    const float* W0   = (const float*)d_in[3];
    const float* b0   = (const float*)d_in[4];
    const float* W1   = (const float*)d_in[5];
    const float* b1   = (const float*)d_in[6];
    const float* Wout = (const float*)d_in[7];
    const float* bout = (const float*)d_in[8];
    float* out = (float*)d_out;

    float* XT    = (float*)d_ws;              // F*B
    float* babsT = XT + F * B;                // F*B
    float* psw   = babsT + F * B;             // NBLK*B (1 MB)
    float* pswy  = psw + NBLK * B;            // NBLK*B (1 MB)

    prep_kernel<<<MLPBLK, 128, 0, stream>>>(X, W0, b0, W1, b1, Wout, bout, XT, babsT);
    nw_partial<<<NBLK, B, 0, stream>>>(XT, babsT, xbg, ybg, psw, pswy);
    nw_final<<<B, 64, 0, stream>>>(psw, pswy, out);
}

// Round 11
// 42.373 us; speedup vs baseline: 3.3634x; 1.1133x over previous
//
#include <hip/hip_runtime.h>

#define B     512
#define NBG   10000
#define F     32
#define H     128
#define CHUNK 20
#define NBLK  500      // NBLK*CHUNK == NBG exactly
#define RB    8        // batch rows per MLP block
#define MLPBLK (B / RB)     // 64

// ---------------- Kernel A: MLP -> XT[f][b], babsT[f][b] ----------------
__global__ __launch_bounds__(128) void prep_kernel(
    const float* __restrict__ X,
    const float* __restrict__ W0, const float* __restrict__ b0,
    const float* __restrict__ W1, const float* __restrict__ b1,
    const float* __restrict__ Wout, const float* __restrict__ bout,
    float* __restrict__ XT,
    float* __restrict__ babsT)
{
    __shared__ __align__(16) float xr[RB * F];
    __shared__ __align__(16) float h0[RB * H];
    __shared__ __align__(16) float h1[RB * H];
    const int t  = threadIdx.x;
    const int r0 = blockIdx.x * RB;

    for (int i = t; i < RB * F; i += 128) {
        int r = i >> 5, f = i & 31;
        float xv = X[(r0 + r) * F + f];
        xr[r * F + f] = xv;
        XT[f * B + r0 + r] = xv;
    }
    __syncthreads();

    float acc[RB];
    #pragma unroll
    for (int r = 0; r < RB; ++r) acc[r] = b0[t];
    #pragma unroll
    for (int f4 = 0; f4 < F / 4; ++f4) {
        float wa = W0[(4*f4+0)*H + t];
        float wb = W0[(4*f4+1)*H + t];
        float wc = W0[(4*f4+2)*H + t];
        float wd = W0[(4*f4+3)*H + t];
        #pragma unroll
        for (int r = 0; r < RB; ++r) {
            float4 xv = *(const float4*)&xr[r * F + 4*f4];
            acc[r] += xv.x*wa + xv.y*wb + xv.z*wc + xv.w*wd;
        }
    }
    #pragma unroll
    for (int r = 0; r < RB; ++r) h0[r * H + t] = fmaxf(acc[r], 0.f);
    __syncthreads();

    #pragma unroll
    for (int r = 0; r < RB; ++r) acc[r] = b1[t];
    #pragma unroll 8
    for (int j4 = 0; j4 < H / 4; ++j4) {
        float wa = W1[(4*j4+0)*H + t];
        float wb = W1[(4*j4+1)*H + t];
        float wc = W1[(4*j4+2)*H + t];
        float wd = W1[(4*j4+3)*H + t];
        #pragma unroll
        for (int r = 0; r < RB; ++r) {
            float4 hv = *(const float4*)&h0[r * H + 4*j4];
            acc[r] += hv.x*wa + hv.y*wb + hv.z*wc + hv.w*wd;
        }
    }
    #pragma unroll
    for (int r = 0; r < RB; ++r) h1[r * H + t] = fmaxf(acc[r], 0.f);
    __syncthreads();

    for (int i = t; i < RB * F; i += 128) {
        int r = i >> 5, f = i & 31;
        float a = bout[f];
        #pragma unroll 8
        for (int j4 = 0; j4 < H / 4; ++j4) {
            float4 hv = *(const float4*)&h1[r * H + 4*j4];
            a += hv.x*Wout[(4*j4+0)*F + f] + hv.y*Wout[(4*j4+1)*F + f]
               + hv.z*Wout[(4*j4+2)*F + f] + hv.w*Wout[(4*j4+3)*F + f];
        }
        babsT[f * B + r0 + r] = fabsf(a);
    }
}

// ---------------- Kernel B: NW partial sums, f-outer / small register state ----------------
// Thread = batch row b. Block = chunk of CHUNK=20 points.
// Per-thread live state: d[20] accumulators + ~15 temps ~= 40 VGPR -- fits
// UNDER the allocator's default 64-reg target, so no remat (r5-r8: VGPR=44,
// 1.3GB L2 re-reads) and no spill (r9: 140MB HBM scratch) is possible.
// Point tile stored TRANSPOSED in LDS: tileT[f][j], rows 20 floats (80B,
// 16B-aligned) -> 5 lane-uniform ds_read_b128 broadcasts per f.
// Per f: 2 coalesced scalar loads (consumed immediately) + 40 VALU.
__global__ __launch_bounds__(512) void nw_partial(
    const float* __restrict__ XT,
    const float* __restrict__ babsT,
    const float* __restrict__ xbg,
    const float* __restrict__ ybg,
    float* __restrict__ psw,
    float* __restrict__ pswy)
{
    __shared__ __align__(16) float tileT[F * CHUNK];   // [32][20], 2560 B
    __shared__ float ytile[CHUNK];

    const int b  = threadIdx.x;
    const int n0 = blockIdx.x * CHUNK;

    // stage chunk transposed: 640 contiguous reads -> tileT[f][n]
    {
        int i = b;                       // i = n*32+f over xbg rows
        float v = xbg[n0 * F + i];
        tileT[(i & 31) * CHUNK + (i >> 5)] = v;
        if (b < CHUNK * F - 512) {
            int i2 = 512 + b;
            float v2 = xbg[n0 * F + i2];
            tileT[(i2 & 31) * CHUNK + (i2 >> 5)] = v2;
        }
        if (b < CHUNK) ytile[b] = ybg[n0 + b];
    }
    __syncthreads();

    float d[CHUNK];
    #pragma unroll
    for (int j = 0; j < CHUNK; ++j) d[j] = 0.f;

    const float* __restrict__ xt = XT + b;
    const float* __restrict__ bt = babsT + b;

    #pragma unroll 2
    for (int f = 0; f < F; ++f) {
        const float xqf = xt[f * B];      // coalesced, L2-resident, used now
        const float bvf = bt[f * B];
        const float4* __restrict__ row = (const float4*)(tileT + f * CHUNK);
        #pragma unroll
        for (int q = 0; q < CHUNK / 4; ++q) {
            float4 v = row[q];            // lane-uniform -> LDS broadcast
            d[4*q+0] += bvf * fabsf(xqf - v.x);
            d[4*q+1] += bvf * fabsf(xqf - v.y);
            d[4*q+2] += bvf * fabsf(xqf - v.z);
            d[4*q+3] += bvf * fabsf(xqf - v.w);
        }
    }

    float sw = 0.f, swy = 0.f;
    #pragma unroll
    for (int j = 0; j < CHUNK; ++j) {
        float w = __expf(-d[j]);
        sw  += w;
        swy += w * ytile[j];
    }

    psw [blockIdx.x * B + b] = sw;    // coalesced
    pswy[blockIdx.x * B + b] = swy;
}

// ---------------- Kernel C: combine partials, normalize ----------------
__global__ __launch_bounds__(64) void nw_final(
    const float* __restrict__ psw,
    const float* __restrict__ pswy,
    float* __restrict__ out)
{
    const int b = blockIdx.x;
    const int t = threadIdx.x;

    float sw = 0.f, swy = 0.f;
    for (int c = t; c < NBLK; c += 64) {
        sw  += psw [c * B + b];
        swy += pswy[c * B + b];
    }
    #pragma unroll
    for (int off = 32; off > 0; off >>= 1) {
        sw  += __shfl_down(sw,  off);
        swy += __shfl_down(swy, off);
    }
    if (t == 0) out[b] = swy / sw;
}

extern "C" void kernel_launch(void* const* d_in, const int* in_sizes, int n_in,
                              void* d_out, int out_size, void* d_ws, size_t ws_size,
                              hipStream_t stream)
{
    const float* X    = (const float*)d_in[0];
    const float* xbg  = (const float*)d_in[1];
    const float* ybg  = (const float*)d_in[2];
    const float* W0   = (const float*)d_in[3];
    const float* b0   = (const float*)d_in[4];
    const float* W1   = (const float*)d_in[5];
    const float* b1   = (const float*)d_in[6];
    const float* Wout = (const float*)d_in[7];
    const float* bout = (const float*)d_in[8];
    float* out = (float*)d_out;

    float* XT    = (float*)d_ws;              // F*B
    float* babsT = XT + F * B;                // F*B
    float* psw   = babsT + F * B;             // NBLK*B (1 MB)
    float* pswy  = psw + NBLK * B;            // NBLK*B (1 MB)

    prep_kernel<<<MLPBLK, 128, 0, stream>>>(X, W0, b0, W1, b1, Wout, bout, XT, babsT);
    nw_partial<<<NBLK, B, 0, stream>>>(XT, babsT, xbg, ybg, psw, pswy);
    nw_final<<<B, 64, 0, stream>>>(psw, pswy, out);
}